// Round 13
// baseline (121.751 us; speedup 1.0000x reference)
//
#include <hip/hip_runtime.h>
#include <hip/hip_bf16.h>

#define BS   8
#define NREL 16
#define NN   512
#define EMB  256

typedef float f32x4 __attribute__((ext_vector_type(4)));
typedef short s16x8 __attribute__((ext_vector_type(8)));

#define GLOBAL_AS __attribute__((address_space(1)))
#define LDS_AS    __attribute__((address_space(3)))

// f32 -> bf16 bits, round-to-nearest-even (cold paths)
__device__ __forceinline__ unsigned short f2bf_bits(float f) {
    union { float f; unsigned u; } v; v.f = f;
    unsigned r = (v.u + 0x7FFFu + ((v.u >> 16) & 1u)) >> 16;
    return (unsigned short)r;
}

// hw cvt path (compiler emits v_cvt_pk_bf16_f32 when paired)
__device__ __forceinline__ unsigned short f2bf_hw(float f) {
    union { __hip_bfloat16 h; unsigned short u; } v;
    v.h = __float2bfloat16(f);
    return v.u;
}

// async global->LDS, 16 bytes per lane (proven correct with __syncthreads in r4)
__device__ __forceinline__ void stage16(const void* g, void* l) {
    __builtin_amdgcn_global_load_lds((const GLOBAL_AS unsigned int*)g,
                                     (LDS_AS unsigned int*)l, 16, 0, 0);
}

// ---------------------------------------------------------------------------
// K0: fused prep.  bid < 1088: transpose W_r + W_0 -> wT[17][h][d] bf16.
//     bid >= 1088: convert F f32 -> Fbf bf16 (512 blocks x 2048 elems).
// ---------------------------------------------------------------------------
__global__ __launch_bounds__(256) void k0_prep(
        const float* __restrict__ Wr, const float* __restrict__ W0,
        const float* __restrict__ F,
        unsigned short* __restrict__ wT, unsigned short* __restrict__ Fbf) {
    int bid = blockIdx.x;
    if (bid < 1088) {
        __shared__ float tile[32][33];
        int rel = bid / 64;          // 0..16
        int t   = bid % 64;
        int d0  = (t & 7) * 32;
        int h0  = (t >> 3) * 32;
        int tx  = threadIdx.x & 31;
        int ty  = threadIdx.x >> 5;  // 0..7
        const float* src = (rel < NREL) ? (Wr + rel * (EMB * EMB)) : W0;
#pragma unroll
        for (int k = 0; k < 4; ++k) {
            int d = d0 + ty + k * 8;
            tile[ty + k * 8][tx] = src[d * EMB + h0 + tx];
        }
        __syncthreads();
#pragma unroll
        for (int k = 0; k < 4; ++k) {
            int h = h0 + ty + k * 8;
            wT[(rel * EMB + h) * EMB + d0 + tx] = f2bf_bits(tile[tx][ty + k * 8]);
        }
    } else {
        long i = ((long)(bid - 1088) * 256 + threadIdx.x) * 8;
        f32x4 x0 = *(const f32x4*)(F + i);
        f32x4 x1 = *(const f32x4*)(F + i + 4);
        s16x8 v;
        v[0] = (short)f2bf_bits(x0[0]); v[1] = (short)f2bf_bits(x0[1]);
        v[2] = (short)f2bf_bits(x0[2]); v[3] = (short)f2bf_bits(x0[3]);
        v[4] = (short)f2bf_bits(x1[0]); v[5] = (short)f2bf_bits(x1[1]);
        v[6] = (short)f2bf_bits(x1[2]); v[7] = (short)f2bf_bits(x1[3]);
        *(s16x8*)(Fbf + i) = v;
    }
}

// ---------------------------------------------------------------------------
// K1: FW[b][rel][m][h] = sum_d F[b][m][d] * W[rel][d][h]
//   D[h][m] = wT(A) x Fbf(B), MFMA 16x16x32 bf16; distance-1 fragment dbuf.
//   rel<16  -> FW fragment-major: [(b*16+rel)*64 + m/8][h][m%8] bf16
//   rel==16 -> F2f f32 row-major [b][n][h]
// ---------------------------------------------------------------------------
__global__ __launch_bounds__(256) void k1_fw(
        const unsigned short* __restrict__ Fbf, const unsigned short* __restrict__ wT,
        unsigned short* __restrict__ FW, float* __restrict__ F2f) {
    int bid = blockIdx.x;
    int b   = bid & 7;
    int q   = bid >> 3;          // 0..135
    int rel = q % 17;
    int mt  = q / 17;            // 0..7
    int tid = threadIdx.x;
    int w   = tid >> 6;          // 0..3
    int l   = tid & 63;
    int lg  = l >> 4;            // 0..3
    int lr  = l & 15;

    int h0 = w * 64;             // wave's 64 h-rows (M-dim)
    int m0 = mt * 64;            // block's 64 m-cols (N-dim)

    const unsigned short* wt = wT + rel * (EMB * EMB) + lg * 8;
    const unsigned short* Fb = Fbf + (long)b * (NN * EMB) + lg * 8;

    f32x4 acc[4][4];
#pragma unroll
    for (int i = 0; i < 4; ++i)
#pragma unroll
        for (int j = 0; j < 4; ++j) acc[i][j] = (f32x4){0.f, 0.f, 0.f, 0.f};

    s16x8 afr[2][4], bfr[2][4];
    // preload kk=0
#pragma unroll
    for (int hi = 0; hi < 4; ++hi)
        afr[0][hi] = *(const s16x8*)(wt + (h0 + hi * 16 + lr) * EMB);
#pragma unroll
    for (int bi = 0; bi < 4; ++bi)
        bfr[0][bi] = *(const s16x8*)(Fb + (m0 + bi * 16 + lr) * EMB);

#pragma unroll
    for (int kk = 0; kk < 8; ++kk) {
        int cur = kk & 1, nxt = cur ^ 1;
        if (kk < 7) {
            int ko = (kk + 1) * 32;
#pragma unroll
            for (int hi = 0; hi < 4; ++hi)
                afr[nxt][hi] = *(const s16x8*)(wt + (h0 + hi * 16 + lr) * EMB + ko);
#pragma unroll
            for (int bi = 0; bi < 4; ++bi)
                bfr[nxt][bi] = *(const s16x8*)(Fb + (m0 + bi * 16 + lr) * EMB + ko);
        }
#pragma unroll
        for (int hi = 0; hi < 4; ++hi)
#pragma unroll
            for (int bi = 0; bi < 4; ++bi)
                acc[hi][bi] = __builtin_amdgcn_mfma_f32_16x16x32_bf16(
                    afr[cur][hi], bfr[cur][bi], acc[hi][bi], 0, 0, 0);
    }

    // Epilogue: D rows = h, cols = m.  C layout: col = lane&15, row = (lane>>4)*4+j
#pragma unroll
    for (int hi = 0; hi < 4; ++hi) {
#pragma unroll
        for (int bi = 0; bi < 4; ++bi) {
            int m  = m0 + bi * 16 + lr;
            int kg = m >> 3, ko = m & 7;
#pragma unroll
            for (int j = 0; j < 4; ++j) {
                int h = h0 + hi * 16 + lg * 4 + j;
                if (rel < NREL)
                    FW[(long)((b * 16 + rel) * 64 + kg) * 2048 + h * 8 + ko] =
                        f2bf_bits(acc[hi][bi][j]);
                else
                    F2f[((long)b * NN + m) * EMB + h] = acc[hi][bi][j];
            }
        }
    }
}

// ---------------------------------------------------------------------------
// K2: part[rg][b][n][h] = sum_{r in rg(2 rels)} sum_m adj[b][r][n][m]*FW[b][r][m][h]
//   grid 512 = 8b (XCD-pinned) x 8nt(64 rows) x 8rg(2 rels)
//   block 256 thr = 4 waves = 2 rh(32-row half) x 2 hh(128-col half)
//   Wave: 32 rows x 128 cols, acc[2][8] = 64 AGPR (occupancy-first: target
//   3-4 blocks/CU so barrier drains overlap across blocks, m114-style).
//   FW slice (16KB, linear fragment-major) staged via global_load_lds w16,
//   double-buffered (32KB LDS).  Each ds_read_b128 feeds 2 MFMAs.
//   K (32 slices over 2 rels) NOT split across waves -> no epilogue reduce.
//   Adjacency distance-1 reg prefetch; one __syncthreads per slice.
// ---------------------------------------------------------------------------
__global__ __launch_bounds__(256, 2) void k2_main(
        const float* __restrict__ adj, const unsigned short* __restrict__ FW,
        float* __restrict__ part) {
    __shared__ unsigned short Blds[2][8192];   // 2 x 16KB slice dbuf
    int bid = blockIdx.x;
    int b   = bid & 7;
    int t   = bid >> 3;          // 0..63
    int nt  = t & 7;
    int rg  = t >> 3;            // 0..7
    int tid = threadIdx.x;
    int w   = tid >> 6;          // 0..3
    int l   = tid & 63;
    int lg  = l >> 4, lr = l & 15;
    int rh  = w >> 1;            // 0..1 : 32-row half
    int hh  = w & 1;             // 0..1 : 128-col half

    int nrow0 = nt * 64 + rh * 32;    // wave's 32 output rows
    int h0    = hh * 128;             // wave's 128 output cols

    f32x4 acc[2][8];
#pragma unroll
    for (int ar = 0; ar < 2; ++ar)
#pragma unroll
        for (int f = 0; f < 8; ++f) acc[ar][f] = (f32x4){0.f, 0.f, 0.f, 0.f};

    // adjacency: row-group ar rows = nrow0 + ar*16 + lr, 32-float chunk at lg*8
    const float* adjb =
        adj + (((long)(b * 16 + rg * 2)) * NN + nrow0 + lr) * NN + lg * 8;
    const unsigned short* fwb = FW + (long)(b * 16 + rg * 2) * 131072;

    f32x4 ax[2][2], ay[2][2];          // [slot][row-group]

    // slice offset in shorts: rel = sl>>4, k32 = sl&15
#define SOFF(sl) ((long)((sl) >> 4) * 131072 + ((sl) & 15) * 8192)

    // ---- prologue: stage slice 0, adjacency slice 0 -> slot 0
    {
        const unsigned short* src = fwb + SOFF(0) + tid * 8;
        unsigned short* dst = &Blds[0][tid * 8];
#pragma unroll
        for (int c = 0; c < 4; ++c) stage16(src + c * 2048, dst + c * 2048);
    }
#pragma unroll
    for (int ar = 0; ar < 2; ++ar) {
        const float* p = adjb + ar * (16 * NN);
        ax[0][ar] = *(const f32x4*)p;
        ay[0][ar] = *(const f32x4*)(p + 4);
    }
    __syncthreads();

#pragma unroll
    for (int s = 0; s < 32; ++s) {
        // 1. stage slice s+1 into the other buffer (async, drains at barrier)
        if (s + 1 < 32) {
            const unsigned short* src = fwb + SOFF(s + 1) + tid * 8;
            unsigned short* dst = &Blds[(s + 1) & 1][tid * 8];
#pragma unroll
            for (int c = 0; c < 4; ++c) stage16(src + c * 2048, dst + c * 2048);
            // 2. adjacency prefetch slice s+1 into the other slot
            long ao = (long)((s + 1) >> 4) * (NN * NN) + ((s + 1) & 15) * 32;
#pragma unroll
            for (int ar = 0; ar < 2; ++ar) {
                const float* p = adjb + ar * (16 * NN) + ao;
                ax[(s + 1) & 1][ar] = *(const f32x4*)p;
                ay[(s + 1) & 1][ar] = *(const f32x4*)(p + 4);
            }
        }

        // 3. convert adjacency slice s -> 2 A-frags (hw v_cvt_pk path)
        s16x8 afr[2];
#pragma unroll
        for (int ar = 0; ar < 2; ++ar) {
            f32x4 x0 = ax[s & 1][ar], x1 = ay[s & 1][ar];
            s16x8 a;
            a[0] = (short)f2bf_hw(x0[0]); a[1] = (short)f2bf_hw(x0[1]);
            a[2] = (short)f2bf_hw(x0[2]); a[3] = (short)f2bf_hw(x0[3]);
            a[4] = (short)f2bf_hw(x1[0]); a[5] = (short)f2bf_hw(x1[1]);
            a[6] = (short)f2bf_hw(x1[2]); a[7] = (short)f2bf_hw(x1[3]);
            afr[ar] = a;
        }

        // 4. B-frags from Blds[s&1] (col half hh); each read feeds 2 MFMAs
        const unsigned short* bl = &Blds[s & 1][lg * 2048];
#pragma unroll
        for (int f = 0; f < 8; ++f) {
            s16x8 bf = *(const s16x8*)(bl + (h0 + f * 16 + lr) * 8);
            acc[0][f] = __builtin_amdgcn_mfma_f32_16x16x32_bf16(afr[0], bf, acc[0][f], 0, 0, 0);
            acc[1][f] = __builtin_amdgcn_mfma_f32_16x16x32_bf16(afr[1], bf, acc[1][f], 0, 0, 0);
        }

        // 5. barrier: drains stage(s+1) + protects buffer reuse
        __syncthreads();
    }
#undef SOFF

    // ---- direct store (no cross-wave reduce: each wave owns its tile)
    float* pp = part + ((long)rg * BS + b) * (NN * EMB);
#pragma unroll
    for (int ar = 0; ar < 2; ++ar) {
#pragma unroll
        for (int f = 0; f < 8; ++f) {
            int h = h0 + f * 16 + lr;
#pragma unroll
            for (int j = 0; j < 4; ++j) {
                int n = nrow0 + ar * 16 + lg * 4 + j;
                pp[(long)n * EMB + h] = acc[ar][f][j];
            }
        }
    }
}

// ---------------------------------------------------------------------------
// K3: out = relu(sum over 8 rg slices + F2f), vectorized f32x4
// ---------------------------------------------------------------------------
__global__ __launch_bounds__(256) void k3_reduce(
        const float* __restrict__ part, const float* __restrict__ F2f,
        float* __restrict__ out) {
    const long PS = (long)BS * NN * EMB;   // 1,048,576 floats per rg slice
    long i = ((long)blockIdx.x * 256 + threadIdx.x) * 4;
    f32x4 s = *(const f32x4*)(part + i);
#pragma unroll
    for (int rg = 1; rg < 8; ++rg)
        s += *(const f32x4*)(part + i + (long)rg * PS);
    s += *(const f32x4*)(F2f + i);
    f32x4 r;
#pragma unroll
    for (int j = 0; j < 4; ++j) r[j] = s[j] > 0.f ? s[j] : 0.f;
    *(f32x4*)(out + i) = r;
}

// ---------------------------------------------------------------------------
extern "C" void kernel_launch(void* const* d_in, const int* in_sizes, int n_in,
                              void* d_out, int out_size, void* d_ws, size_t ws_size,
                              hipStream_t stream) {
    const float* F   = (const float*)d_in[0];   // [8][512][256]
    const float* adj = (const float*)d_in[1];   // [8][16][512][512]
    const float* Wr  = (const float*)d_in[2];   // [16][256][256]
    const float* W0  = (const float*)d_in[3];   // [256][256]
    float* out = (float*)d_out;                 // [8][512][256]

    unsigned short* wT  = (unsigned short*)d_ws;             // 17*256*256 bf16
    unsigned short* Fbf = wT + 17 * 256 * 256;               // 8*512*256 bf16
    unsigned short* FW  = Fbf + (long)8 * 512 * 256;         // 8*16*64*2048 bf16
    float* F2f  = (float*)(FW + (long)8 * 16 * 64 * 2048);   // 8*512*256 f32
    float* part = F2f + (long)8 * 512 * 256;                 // 8*8*512*256 f32

    k0_prep<<<1600, 256, 0, stream>>>(Wr, W0, F, wT, Fbf);
    k1_fw<<<1088, 256, 0, stream>>>(Fbf, wT, FW, F2f);
    k2_main<<<512, 256, 0, stream>>>(adj, FW, part);
    k3_reduce<<<1024, 256, 0, stream>>>(part, F2f, out);
}

// Round 14
// 121.704 us; speedup vs baseline: 1.0004x; 1.0004x over previous
//
#include <hip/hip_runtime.h>
#include <hip/hip_bf16.h>

#define BS   8
#define NREL 16
#define NN   512
#define EMB  256

typedef float f32x4 __attribute__((ext_vector_type(4)));
typedef short s16x8 __attribute__((ext_vector_type(8)));

#define GLOBAL_AS __attribute__((address_space(1)))
#define LDS_AS    __attribute__((address_space(3)))

// f32 -> bf16 bits, round-to-nearest-even (cold paths)
__device__ __forceinline__ unsigned short f2bf_bits(float f) {
    union { float f; unsigned u; } v; v.f = f;
    unsigned r = (v.u + 0x7FFFu + ((v.u >> 16) & 1u)) >> 16;
    return (unsigned short)r;
}

// hw cvt path (compiler emits v_cvt_pk_bf16_f32 when paired)
__device__ __forceinline__ unsigned short f2bf_hw(float f) {
    union { __hip_bfloat16 h; unsigned short u; } v;
    v.h = __float2bfloat16(f);
    return v.u;
}

// async global->LDS, 16 bytes per lane
__device__ __forceinline__ void stage16(const void* g, void* l) {
    __builtin_amdgcn_global_load_lds((const GLOBAL_AS unsigned int*)g,
                                     (LDS_AS unsigned int*)l, 16, 0, 0);
}

// ---------------------------------------------------------------------------
// K0: fused prep.  bid < 1088: transpose W_r + W_0 -> wT[17][h][d] bf16.
//     bid >= 1088: convert F f32 -> Fbf bf16 (512 blocks x 2048 elems).
// ---------------------------------------------------------------------------
__global__ __launch_bounds__(256) void k0_prep(
        const float* __restrict__ Wr, const float* __restrict__ W0,
        const float* __restrict__ F,
        unsigned short* __restrict__ wT, unsigned short* __restrict__ Fbf) {
    int bid = blockIdx.x;
    if (bid < 1088) {
        __shared__ float tile[32][33];
        int rel = bid / 64;          // 0..16
        int t   = bid % 64;
        int d0  = (t & 7) * 32;
        int h0  = (t >> 3) * 32;
        int tx  = threadIdx.x & 31;
        int ty  = threadIdx.x >> 5;  // 0..7
        const float* src = (rel < NREL) ? (Wr + rel * (EMB * EMB)) : W0;
#pragma unroll
        for (int k = 0; k < 4; ++k) {
            int d = d0 + ty + k * 8;
            tile[ty + k * 8][tx] = src[d * EMB + h0 + tx];
        }
        __syncthreads();
#pragma unroll
        for (int k = 0; k < 4; ++k) {
            int h = h0 + ty + k * 8;
            wT[(rel * EMB + h) * EMB + d0 + tx] = f2bf_bits(tile[tx][ty + k * 8]);
        }
    } else {
        long i = ((long)(bid - 1088) * 256 + threadIdx.x) * 8;
        f32x4 x0 = *(const f32x4*)(F + i);
        f32x4 x1 = *(const f32x4*)(F + i + 4);
        s16x8 v;
        v[0] = (short)f2bf_bits(x0[0]); v[1] = (short)f2bf_bits(x0[1]);
        v[2] = (short)f2bf_bits(x0[2]); v[3] = (short)f2bf_bits(x0[3]);
        v[4] = (short)f2bf_bits(x1[0]); v[5] = (short)f2bf_bits(x1[1]);
        v[6] = (short)f2bf_bits(x1[2]); v[7] = (short)f2bf_bits(x1[3]);
        *(s16x8*)(Fbf + i) = v;
    }
}

// ---------------------------------------------------------------------------
// K1: FW[b][rel][m][h] = sum_d F[b][m][d] * W[rel][d][h]
//   D[h][m] = wT(A) x Fbf(B), MFMA 16x16x32 bf16; distance-1 fragment dbuf.
//   rel<16  -> FW fragment-major: [(b*16+rel)*64 + m/8][h][m%8] bf16
//   rel==16 -> F2f f32 row-major [b][n][h]
// ---------------------------------------------------------------------------
__global__ __launch_bounds__(256) void k1_fw(
        const unsigned short* __restrict__ Fbf, const unsigned short* __restrict__ wT,
        unsigned short* __restrict__ FW, float* __restrict__ F2f) {
    int bid = blockIdx.x;
    int b   = bid & 7;
    int q   = bid >> 3;          // 0..135
    int rel = q % 17;
    int mt  = q / 17;            // 0..7
    int tid = threadIdx.x;
    int w   = tid >> 6;          // 0..3
    int l   = tid & 63;
    int lg  = l >> 4;            // 0..3
    int lr  = l & 15;

    int h0 = w * 64;             // wave's 64 h-rows (M-dim)
    int m0 = mt * 64;            // block's 64 m-cols (N-dim)

    const unsigned short* wt = wT + rel * (EMB * EMB) + lg * 8;
    const unsigned short* Fb = Fbf + (long)b * (NN * EMB) + lg * 8;

    f32x4 acc[4][4];
#pragma unroll
    for (int i = 0; i < 4; ++i)
#pragma unroll
        for (int j = 0; j < 4; ++j) acc[i][j] = (f32x4){0.f, 0.f, 0.f, 0.f};

    s16x8 afr[2][4], bfr[2][4];
    // preload kk=0
#pragma unroll
    for (int hi = 0; hi < 4; ++hi)
        afr[0][hi] = *(const s16x8*)(wt + (h0 + hi * 16 + lr) * EMB);
#pragma unroll
    for (int bi = 0; bi < 4; ++bi)
        bfr[0][bi] = *(const s16x8*)(Fb + (m0 + bi * 16 + lr) * EMB);

#pragma unroll
    for (int kk = 0; kk < 8; ++kk) {
        int cur = kk & 1, nxt = cur ^ 1;
        if (kk < 7) {
            int ko = (kk + 1) * 32;
#pragma unroll
            for (int hi = 0; hi < 4; ++hi)
                afr[nxt][hi] = *(const s16x8*)(wt + (h0 + hi * 16 + lr) * EMB + ko);
#pragma unroll
            for (int bi = 0; bi < 4; ++bi)
                bfr[nxt][bi] = *(const s16x8*)(Fb + (m0 + bi * 16 + lr) * EMB + ko);
        }
#pragma unroll
        for (int hi = 0; hi < 4; ++hi)
#pragma unroll
            for (int bi = 0; bi < 4; ++bi)
                acc[hi][bi] = __builtin_amdgcn_mfma_f32_16x16x32_bf16(
                    afr[cur][hi], bfr[cur][bi], acc[hi][bi], 0, 0, 0);
    }

    // Epilogue: D rows = h, cols = m.  C layout: col = lane&15, row = (lane>>4)*4+j
#pragma unroll
    for (int hi = 0; hi < 4; ++hi) {
#pragma unroll
        for (int bi = 0; bi < 4; ++bi) {
            int m  = m0 + bi * 16 + lr;
            int kg = m >> 3, ko = m & 7;
#pragma unroll
            for (int j = 0; j < 4; ++j) {
                int h = h0 + hi * 16 + lg * 4 + j;
                if (rel < NREL)
                    FW[(long)((b * 16 + rel) * 64 + kg) * 2048 + h * 8 + ko] =
                        f2bf_bits(acc[hi][bi][j]);
                else
                    F2f[((long)b * NN + m) * EMB + h] = acc[hi][bi][j];
            }
        }
    }
}

// ---------------------------------------------------------------------------
// K2: part[rg][b][n][h] = sum_{slices} adj[b][r][n][m]*FW[b][r][m][h]
//   template NSL = K-slices per block (16 -> 1 rel, grid 1024, 4 blk/CU;
//                                      32 -> 2 rels, grid 512 fallback)
//   block 256 thr = 4 waves = 2 rh(32-row half) x 2 hh(128-col half)
//   Wave: 32 rows x 128 cols, acc[2][8] = 64 AGPR; arch VGPR ~48 -> unified
//   ~112 <= 128 -> 16 waves/CU at grid 1024.  __launch_bounds__(256,4).
//   Pipeline order (r4 lesson): compute(s) -> __syncthreads (drains stage(s+1),
//   issued a FULL iteration earlier) -> issue stage(s+2) + adj(s+2).
// ---------------------------------------------------------------------------
template<int NSL>
__global__ __launch_bounds__(256, 4) void k2_main(
        const float* __restrict__ adj, const unsigned short* __restrict__ FW,
        float* __restrict__ part) {
    __shared__ unsigned short Blds[2][8192];   // 2 x 16KB slice dbuf
    const int RELS = NSL / 16;                 // rels per block (1 or 2)
    int bid = blockIdx.x;
    int b   = bid & 7;
    int t   = bid >> 3;
    int nt  = t & 7;
    int rg  = t >> 3;            // 0..(256/NSL - 1)
    int tid = threadIdx.x;
    int w   = tid >> 6;          // 0..3
    int l   = tid & 63;
    int lg  = l >> 4, lr = l & 15;
    int rh  = w >> 1;            // 0..1 : 32-row half
    int hh  = w & 1;             // 0..1 : 128-col half

    int nrow0 = nt * 64 + rh * 32;    // wave's 32 output rows
    int h0    = hh * 128;             // wave's 128 output cols

    f32x4 acc[2][8];
#pragma unroll
    for (int ar = 0; ar < 2; ++ar)
#pragma unroll
        for (int f = 0; f < 8; ++f) acc[ar][f] = (f32x4){0.f, 0.f, 0.f, 0.f};

    const float* adjb =
        adj + (((long)(b * 16 + rg * RELS)) * NN + nrow0 + lr) * NN + lg * 8;
    const unsigned short* fwb = FW + (long)(b * 16 + rg * RELS) * 131072;

    f32x4 ax[2][2], ay[2][2];          // [slot][row-group]

#define SOFF(sl) ((long)((sl) >> 4) * 131072 + ((sl) & 15) * 8192)
#define AOFF(sl) ((long)((sl) >> 4) * (NN * NN) + ((sl) & 15) * 32)

    // ---- prologue: stage slices 0,1; adj slices 0,1
    {
        const unsigned short* s0 = fwb + SOFF(0) + tid * 8;
        unsigned short* d0 = &Blds[0][tid * 8];
#pragma unroll
        for (int c = 0; c < 4; ++c) stage16(s0 + c * 2048, d0 + c * 2048);
        const unsigned short* s1 = fwb + SOFF(1) + tid * 8;
        unsigned short* d1 = &Blds[1][tid * 8];
#pragma unroll
        for (int c = 0; c < 4; ++c) stage16(s1 + c * 2048, d1 + c * 2048);
    }
#pragma unroll
    for (int sl = 0; sl < 2; ++sl)
#pragma unroll
        for (int ar = 0; ar < 2; ++ar) {
            const float* p = adjb + ar * (16 * NN) + AOFF(sl);
            ax[sl][ar] = *(const f32x4*)p;
            ay[sl][ar] = *(const f32x4*)(p + 4);
        }
    __syncthreads();

#pragma unroll
    for (int s = 0; s < NSL; ++s) {
        // 1. compute slice s: convert adj regs -> A-frags, B from Blds[s&1]
        s16x8 afr[2];
#pragma unroll
        for (int ar = 0; ar < 2; ++ar) {
            f32x4 x0 = ax[s & 1][ar], x1 = ay[s & 1][ar];
            s16x8 a;
            a[0] = (short)f2bf_hw(x0[0]); a[1] = (short)f2bf_hw(x0[1]);
            a[2] = (short)f2bf_hw(x0[2]); a[3] = (short)f2bf_hw(x0[3]);
            a[4] = (short)f2bf_hw(x1[0]); a[5] = (short)f2bf_hw(x1[1]);
            a[6] = (short)f2bf_hw(x1[2]); a[7] = (short)f2bf_hw(x1[3]);
            afr[ar] = a;
        }
        const unsigned short* bl = &Blds[s & 1][lg * 2048];
#pragma unroll
        for (int f = 0; f < 8; ++f) {
            s16x8 bf = *(const s16x8*)(bl + (h0 + f * 16 + lr) * 8);
            acc[0][f] = __builtin_amdgcn_mfma_f32_16x16x32_bf16(afr[0], bf, acc[0][f], 0, 0, 0);
            acc[1][f] = __builtin_amdgcn_mfma_f32_16x16x32_bf16(afr[1], bf, acc[1][f], 0, 0, 0);
        }

        // 2. barrier: drains stage(s+1) (issued one full iteration ago)
        __syncthreads();

        // 3. issue stage(s+2) into buf[s&1] (all reads of it done) + adj(s+2)
        if (s + 2 < NSL) {
            const unsigned short* src = fwb + SOFF(s + 2) + tid * 8;
            unsigned short* dst = &Blds[s & 1][tid * 8];
#pragma unroll
            for (int c = 0; c < 4; ++c) stage16(src + c * 2048, dst + c * 2048);
            long ao = AOFF(s + 2);
#pragma unroll
            for (int ar = 0; ar < 2; ++ar) {
                const float* p = adjb + ar * (16 * NN) + ao;
                ax[s & 1][ar] = *(const f32x4*)p;
                ay[s & 1][ar] = *(const f32x4*)(p + 4);
            }
        }
    }
#undef SOFF
#undef AOFF

    // ---- direct store (each wave owns its 32x128 tile)
    float* pp = part + ((long)rg * BS + b) * (NN * EMB);
#pragma unroll
    for (int ar = 0; ar < 2; ++ar) {
#pragma unroll
        for (int f = 0; f < 8; ++f) {
            int h = h0 + f * 16 + lr;
#pragma unroll
            for (int j = 0; j < 4; ++j) {
                int n = nrow0 + ar * 16 + lg * 4 + j;
                pp[(long)n * EMB + h] = acc[ar][f][j];
            }
        }
    }
}

// ---------------------------------------------------------------------------
// K3: out = relu(sum over NS part slices + F2f), vectorized f32x4
// ---------------------------------------------------------------------------
template<int NS>
__global__ __launch_bounds__(256) void k3_reduce(
        const float* __restrict__ part, const float* __restrict__ F2f,
        float* __restrict__ out) {
    const long PS = (long)BS * NN * EMB;   // 1,048,576 floats per slice
    long i = ((long)blockIdx.x * 256 + threadIdx.x) * 4;
    f32x4 s = *(const f32x4*)(part + i);
#pragma unroll
    for (int rg = 1; rg < NS; ++rg)
        s += *(const f32x4*)(part + i + (long)rg * PS);
    s += *(const f32x4*)(F2f + i);
    f32x4 r;
#pragma unroll
    for (int j = 0; j < 4; ++j) r[j] = s[j] > 0.f ? s[j] : 0.f;
    *(f32x4*)(out + i) = r;
}

// ---------------------------------------------------------------------------
extern "C" void kernel_launch(void* const* d_in, const int* in_sizes, int n_in,
                              void* d_out, int out_size, void* d_ws, size_t ws_size,
                              hipStream_t stream) {
    const float* F   = (const float*)d_in[0];   // [8][512][256]
    const float* adj = (const float*)d_in[1];   // [8][16][512][512]
    const float* Wr  = (const float*)d_in[2];   // [16][256][256]
    const float* W0  = (const float*)d_in[3];   // [256][256]
    float* out = (float*)d_out;                 // [8][512][256]

    unsigned short* wT  = (unsigned short*)d_ws;             // 17*256*256 bf16
    unsigned short* Fbf = wT + 17 * 256 * 256;               // 8*512*256 bf16
    unsigned short* FW  = Fbf + (long)8 * 512 * 256;         // 8*16*64*2048 bf16
    float* F2f  = (float*)(FW + (long)8 * 16 * 64 * 2048);   // 8*512*256 f32
    float* part = F2f + (long)8 * 512 * 256;                 // up to 16 slices f32

    k0_prep<<<1600, 256, 0, stream>>>(Wr, W0, F, wT, Fbf);
    k1_fw<<<1088, 256, 0, stream>>>(Fbf, wT, FW, F2f);

    // 16-slice part needs 109,182,976 B of ws; fall back to 8 slices otherwise
    const size_t need16 = 42074112ull + 67108864ull;
    if (ws_size >= need16) {
        k2_main<16><<<1024, 256, 0, stream>>>(adj, FW, part);
        k3_reduce<16><<<1024, 256, 0, stream>>>(part, F2f, out);
    } else {
        k2_main<32><<<512, 256, 0, stream>>>(adj, FW, part);
        k3_reduce<8><<<1024, 256, 0, stream>>>(part, F2f, out);
    }
}

// Round 15
// 107.914 us; speedup vs baseline: 1.1282x; 1.1278x over previous
//
#include <hip/hip_runtime.h>
#include <hip/hip_bf16.h>

#define BS   8
#define NREL 16
#define NN   512
#define EMB  256

typedef float f32x4 __attribute__((ext_vector_type(4)));
typedef short s16x4 __attribute__((ext_vector_type(4)));
typedef short s16x8 __attribute__((ext_vector_type(8)));

// f32 -> bf16 bits, round-to-nearest-even (cold paths)
__device__ __forceinline__ unsigned short f2bf_bits(float f) {
    union { float f; unsigned u; } v; v.f = f;
    unsigned r = (v.u + 0x7FFFu + ((v.u >> 16) & 1u)) >> 16;
    return (unsigned short)r;
}

// hw cvt path (compiler emits v_cvt_pk_bf16_f32 when paired)
__device__ __forceinline__ unsigned short f2bf_hw(float f) {
    union { __hip_bfloat16 h; unsigned short u; } v;
    v.h = __float2bfloat16(f);
    return v.u;
}

// ---------------------------------------------------------------------------
// K0: 3-way prep.
//  bid < 1088          : transpose W_r + W_0 -> wT[17][h][d] bf16
//  1088 <= bid < 2112  : FT_c[b][mc][d][ml] = F[b][mc*32+ml][d] bf16 (chunked
//                        transpose; chunk (b,mc) = 16KB contiguous)
//  bid >= 2112         : Fbf row-major bf16 convert of F
// ---------------------------------------------------------------------------
__global__ __launch_bounds__(256) void k0_prep(
        const float* __restrict__ Wr, const float* __restrict__ W0,
        const float* __restrict__ F,
        unsigned short* __restrict__ wT, unsigned short* __restrict__ Fbf,
        unsigned short* __restrict__ FTc) {
    __shared__ float tile[32][33];
    int bid = blockIdx.x;
    int tx  = threadIdx.x & 31;
    int ty  = threadIdx.x >> 5;  // 0..7
    if (bid < 1088) {
        int rel = bid / 64;          // 0..16
        int t   = bid % 64;
        int d0  = (t & 7) * 32;
        int h0  = (t >> 3) * 32;
        const float* src = (rel < NREL) ? (Wr + rel * (EMB * EMB)) : W0;
#pragma unroll
        for (int k = 0; k < 4; ++k)
            tile[ty + k * 8][tx] = src[(d0 + ty + k * 8) * EMB + h0 + tx];
        __syncthreads();
#pragma unroll
        for (int k = 0; k < 4; ++k)
            wT[(rel * EMB + h0 + ty + k * 8) * EMB + d0 + tx] =
                f2bf_bits(tile[tx][ty + k * 8]);
    } else if (bid < 2112) {
        int q   = bid - 1088;        // 0..1023
        int b   = q >> 7;            // 0..7
        int rem = q & 127;
        int mc  = rem >> 3;          // 0..15
        int dc  = rem & 7;           // 0..7
        const float* src = F + ((long)b * NN + mc * 32) * EMB + dc * 32;
#pragma unroll
        for (int k = 0; k < 4; ++k)
            tile[ty + k * 8][tx] = src[(ty + k * 8) * EMB + tx];  // [m][d]
        __syncthreads();
        unsigned short* dst = FTc + ((long)(b * 16 + mc) * 256 + dc * 32) * 32;
#pragma unroll
        for (int k = 0; k < 4; ++k)
            dst[(ty + k * 8) * 32 + tx] = f2bf_bits(tile[tx][ty + k * 8]);
    } else {
        long i = ((long)(bid - 2112) * 256 + threadIdx.x) * 8;
        f32x4 x0 = *(const f32x4*)(F + i);
        f32x4 x1 = *(const f32x4*)(F + i + 4);
        s16x8 v;
        v[0] = (short)f2bf_bits(x0[0]); v[1] = (short)f2bf_bits(x0[1]);
        v[2] = (short)f2bf_bits(x0[2]); v[3] = (short)f2bf_bits(x0[3]);
        v[4] = (short)f2bf_bits(x1[0]); v[5] = (short)f2bf_bits(x1[1]);
        v[6] = (short)f2bf_bits(x1[2]); v[7] = (short)f2bf_bits(x1[3]);
        *(s16x8*)(Fbf + i) = v;
    }
}

// ---------------------------------------------------------------------------
// K2F: fully fused. out[b][n][h] = relu( sum_r (adj_br @ F_b) @ W_r + F_b @ W0 )
//   grid 256 = 8b (XCD-pinned) x 32nt(16 rows).  block 512 thr = 8 waves.
//   Wave w, pass p: r = 2w+p.
//   Phase 1 (per pass): msg^T[d=256][n=16] = FT(A) x adj(B); FT chunks
//     (16KB = [256 d][32 m]) reg-staged to LDS dbuf, lgkm-only barriers
//     (r8/r11 discipline, no vmcnt(0) in loop); adj dist-1 reg prefetch.
//   Park: msg^T -> bf16 -> wave-private msgL (B-frag layout [d/8][n][d%8]).
//   Phase 2: out^T[h=256][n=16] += wT[r](A, global L2) x msgL(B).  No barriers.
//   W0: wave 0 adds wT[16](A) x Fbf-rows(B).
//   Epilogue: 3-round LDS tree reduce over 8 waves, relu, single store.
//   Layout safety: A and B frags use the SAME (lg,e)->k formula everywhere
//   (permutation-consistent); C/D mapping is the verified col=lane&15 one.
// ---------------------------------------------------------------------------
__global__ __launch_bounds__(512, 2) void k2f_fused(
        const float* __restrict__ adj, const unsigned short* __restrict__ wT,
        const unsigned short* __restrict__ FTc,
        const unsigned short* __restrict__ Fbf, float* __restrict__ out) {
    __shared__ unsigned short FTl[2][8192];   // 2 x 16KB FT chunk dbuf
    __shared__ unsigned short msgL[8][4096];  // 8KB per wave (msg^T bf16)
    int bid = blockIdx.x;
    int b   = bid & 7;
    int nt  = bid >> 3;          // 0..31
    int n0  = nt * 16;
    int tid = threadIdx.x;
    int w   = tid >> 6;          // 0..7
    int l   = tid & 63;
    int lg  = l >> 4, lr = l & 15;

    f32x4 oacc[16];
#pragma unroll
    for (int i = 0; i < 16; ++i) oacc[i] = (f32x4){0.f, 0.f, 0.f, 0.f};

    const unsigned short* ftc_b = FTc + (long)b * 16 * 8192;

    s16x8 st0, st1;              // FT chunk staging regs (32B/thread)
    f32x4 ax[2], ay[2];          // adjacency dist-1 ping-pong

    for (int p = 0; p < 2; ++p) {
        int r = 2 * w + p;
        const float* adjr =
            adj + ((long)((b * 16 + r) * NN + n0 + lr)) * NN + lg * 8;
        const unsigned short* wtr = wT + (long)r * 65536 + lr * 256 + lg * 8;

        // ---- prologue: chunk0 -> LDS, chunk1 -> regs, adj mc0 -> slot0
        {
            const unsigned short* s = ftc_b + tid * 8;
            st0 = *(const s16x8*)(s);
            st1 = *(const s16x8*)(s + 4096);
            *(s16x8*)(&FTl[0][tid * 8]) = st0;
            *(s16x8*)(&FTl[0][tid * 8 + 4096]) = st1;
            const unsigned short* s1 = ftc_b + 8192 + tid * 8;
            st0 = *(const s16x8*)(s1);
            st1 = *(const s16x8*)(s1 + 4096);
        }
        ax[0] = *(const f32x4*)(adjr);
        ay[0] = *(const f32x4*)(adjr + 4);
        asm volatile("s_waitcnt lgkmcnt(0)" ::: "memory");
        __builtin_amdgcn_sched_barrier(0);
        __builtin_amdgcn_s_barrier();
        asm volatile("" ::: "memory");

        f32x4 macc[16];
#pragma unroll
        for (int i = 0; i < 16; ++i) macc[i] = (f32x4){0.f, 0.f, 0.f, 0.f};

        // ---- phase 1: msg^T = FT x adj over 16 m-chunks
#pragma unroll
        for (int mc = 0; mc < 16; ++mc) {
            if (mc + 1 < 16) {   // adj prefetch (dist-1)
                const float* pa = adjr + (mc + 1) * 32;
                ax[(mc + 1) & 1] = *(const f32x4*)pa;
                ay[(mc + 1) & 1] = *(const f32x4*)(pa + 4);
            }
            // B-frag: adjacency (k=m, col=n)
            f32x4 x0 = ax[mc & 1], x1 = ay[mc & 1];
            s16x8 bfr;
            bfr[0] = (short)f2bf_hw(x0[0]); bfr[1] = (short)f2bf_hw(x0[1]);
            bfr[2] = (short)f2bf_hw(x0[2]); bfr[3] = (short)f2bf_hw(x0[3]);
            bfr[4] = (short)f2bf_hw(x1[0]); bfr[5] = (short)f2bf_hw(x1[1]);
            bfr[6] = (short)f2bf_hw(x1[2]); bfr[7] = (short)f2bf_hw(x1[3]);
            // A-frags: FT chunk [d][32m]; row d = fi*16+lr, k-chunk lg*8
            const unsigned short* al = &FTl[mc & 1][lr * 32 + lg * 8];
#pragma unroll
            for (int fi = 0; fi < 16; ++fi) {
                s16x8 af = *(const s16x8*)(al + fi * 512);
                macc[fi] = __builtin_amdgcn_mfma_f32_16x16x32_bf16(
                    af, bfr, macc[fi], 0, 0, 0);
            }
            asm volatile("" ::: "memory");   // ds_reads above, ds_writes below
            if (mc + 1 < 16) {
                unsigned short* d = &FTl[(mc + 1) & 1][tid * 8];
                *(s16x8*)(d) = st0;
                *(s16x8*)(d + 4096) = st1;
                if (mc + 2 < 16) {
                    const unsigned short* s =
                        ftc_b + (long)(mc + 2) * 8192 + tid * 8;
                    st0 = *(const s16x8*)(s);
                    st1 = *(const s16x8*)(s + 4096);
                }
                asm volatile("s_waitcnt lgkmcnt(0)" ::: "memory");
                __builtin_amdgcn_sched_barrier(0);
                __builtin_amdgcn_s_barrier();
                asm volatile("" ::: "memory");
            }
        }

        // ---- park msg^T as bf16 in wave-private msgL (B-frag layout)
        // d = fi*16 + lg*4 + j  ->  kg = 2fi+(lg>>1), ko = (lg&1)*4+j, n = lr
        {
            unsigned short* ml = &msgL[w][lr * 8 + (lg & 1) * 4];
#pragma unroll
            for (int fi = 0; fi < 16; ++fi) {
                s16x4 v;
                v[0] = (short)f2bf_hw(macc[fi][0]);
                v[1] = (short)f2bf_hw(macc[fi][1]);
                v[2] = (short)f2bf_hw(macc[fi][2]);
                v[3] = (short)f2bf_hw(macc[fi][3]);
                *(s16x4*)(ml + (2 * fi + (lg >> 1)) * 128) = v;
            }
        }

        // ---- phase 2: out^T += wT[r] x msg^T   (wave-private, no barriers)
#pragma unroll
        for (int kk8 = 0; kk8 < 8; ++kk8) {
            s16x8 bm = *(const s16x8*)(&msgL[w][(kk8 * 4 + lg) * 128 + lr * 8]);
#pragma unroll
            for (int hi = 0; hi < 16; ++hi) {
                s16x8 wa = *(const s16x8*)(wtr + hi * 4096 + kk8 * 32);
                oacc[hi] = __builtin_amdgcn_mfma_f32_16x16x32_bf16(
                    wa, bm, oacc[hi], 0, 0, 0);
            }
        }
    }

    // ---- W0 path (wave 0 only; added once, summed in the reduce)
    if (w == 0) {
        const unsigned short* wt16 = wT + (long)16 * 65536 + lr * 256 + lg * 8;
        const unsigned short* fb =
            Fbf + ((long)(b * NN + n0 + lr)) * EMB + lg * 8;
#pragma unroll
        for (int kk8 = 0; kk8 < 8; ++kk8) {
            s16x8 bf = *(const s16x8*)(fb + kk8 * 32);
#pragma unroll
            for (int hi = 0; hi < 16; ++hi) {
                s16x8 wa = *(const s16x8*)(wt16 + hi * 4096 + kk8 * 32);
                oacc[hi] = __builtin_amdgcn_mfma_f32_16x16x32_bf16(
                    wa, bf, oacc[hi], 0, 0, 0);
            }
        }
    }

    // ---- epilogue: 3-round tree reduce over 8 waves via LDS (reuse msgL)
    __syncthreads();
    float* lf = (float*)msgL;    // 16384 floats = 64KB (4 regions x 4096)
    if (w >= 4) {
#pragma unroll
        for (int fi = 0; fi < 16; ++fi)
            *(f32x4*)(lf + (w - 4) * 4096 + fi * 256 + l * 4) = oacc[fi];
    }
    __syncthreads();
    if (w < 4) {
#pragma unroll
        for (int fi = 0; fi < 16; ++fi)
            oacc[fi] += *(const f32x4*)(lf + w * 4096 + fi * 256 + l * 4);
    }
    __syncthreads();
    if (w == 2 || w == 3) {
#pragma unroll
        for (int fi = 0; fi < 16; ++fi)
            *(f32x4*)(lf + (w - 2) * 4096 + fi * 256 + l * 4) = oacc[fi];
    }
    __syncthreads();
    if (w < 2) {
#pragma unroll
        for (int fi = 0; fi < 16; ++fi)
            oacc[fi] += *(const f32x4*)(lf + w * 4096 + fi * 256 + l * 4);
    }
    __syncthreads();
    if (w == 1) {
#pragma unroll
        for (int fi = 0; fi < 16; ++fi)
            *(f32x4*)(lf + fi * 256 + l * 4) = oacc[fi];
    }
    __syncthreads();
    if (w == 0) {
        float* po = out + ((long)(b * NN + n0 + lr)) * EMB;
#pragma unroll
        for (int fi = 0; fi < 16; ++fi) {
            f32x4 v = oacc[fi] + *(const f32x4*)(lf + fi * 256 + l * 4);
            f32x4 rv;
#pragma unroll
            for (int j = 0; j < 4; ++j) rv[j] = v[j] > 0.f ? v[j] : 0.f;
            *(f32x4*)(po + fi * 16 + lg * 4) = rv;
        }
    }
}

// ---------------------------------------------------------------------------
extern "C" void kernel_launch(void* const* d_in, const int* in_sizes, int n_in,
                              void* d_out, int out_size, void* d_ws, size_t ws_size,
                              hipStream_t stream) {
    const float* F   = (const float*)d_in[0];   // [8][512][256]
    const float* adj = (const float*)d_in[1];   // [8][16][512][512]
    const float* Wr  = (const float*)d_in[2];   // [16][256][256]
    const float* W0  = (const float*)d_in[3];   // [256][256]
    float* out = (float*)d_out;                 // [8][512][256]

    unsigned short* wT  = (unsigned short*)d_ws;           // 17*256*256
    unsigned short* Fbf = wT + 17 * 256 * 256;             // 8*512*256
    unsigned short* FTc = Fbf + (long)8 * 512 * 256;       // 8*16*256*32

    k0_prep<<<2624, 256, 0, stream>>>(Wr, W0, F, wT, Fbf, FTc);
    k2f_fused<<<256, 512, 0, stream>>>(adj, wT, FTc, Fbf, out);
}

// Round 16
// 94.534 us; speedup vs baseline: 1.2879x; 1.1415x over previous
//
#include <hip/hip_runtime.h>
#include <hip/hip_bf16.h>

#define BS   8
#define NREL 16
#define NN   512
#define EMB  256

typedef float f32x4 __attribute__((ext_vector_type(4)));
typedef short s16x8 __attribute__((ext_vector_type(8)));

// f32 -> bf16 bits, round-to-nearest-even
__device__ __forceinline__ unsigned short f2bf_bits(float f) {
    union { float f; unsigned u; } v; v.f = f;
    unsigned r = (v.u + 0x7FFFu + ((v.u >> 16) & 1u)) >> 16;
    return (unsigned short)r;
}

__device__ __forceinline__ float bf2f(unsigned short u) {
    union { unsigned u; float f; } v; v.u = ((unsigned)u) << 16;
    return v.f;
}

// hw cvt path (compiler emits v_cvt_pk_bf16_f32 when paired)
__device__ __forceinline__ unsigned short f2bf_hw(float f) {
    union { __hip_bfloat16 h; unsigned short u; } v;
    v.h = __float2bfloat16(f);
    return v.u;
}

// ---------------------------------------------------------------------------
// K0: fused prep.  bid < 1088: transpose W_r + W_0 -> wT[17][h][d] bf16.
//     bid >= 1088: convert F f32 -> Fbf bf16 (512 blocks x 2048 elems).
// ---------------------------------------------------------------------------
__global__ __launch_bounds__(256) void k0_prep(
        const float* __restrict__ Wr, const float* __restrict__ W0,
        const float* __restrict__ F,
        unsigned short* __restrict__ wT, unsigned short* __restrict__ Fbf) {
    int bid = blockIdx.x;
    if (bid < 1088) {
        __shared__ float tile[32][33];
        int rel = bid / 64;          // 0..16
        int t   = bid % 64;
        int d0  = (t & 7) * 32;
        int h0  = (t >> 3) * 32;
        int tx  = threadIdx.x & 31;
        int ty  = threadIdx.x >> 5;  // 0..7
        const float* src = (rel < NREL) ? (Wr + rel * (EMB * EMB)) : W0;
#pragma unroll
        for (int k = 0; k < 4; ++k) {
            int d = d0 + ty + k * 8;
            tile[ty + k * 8][tx] = src[d * EMB + h0 + tx];
        }
        __syncthreads();
#pragma unroll
        for (int k = 0; k < 4; ++k) {
            int h = h0 + ty + k * 8;
            wT[(rel * EMB + h) * EMB + d0 + tx] = f2bf_bits(tile[tx][ty + k * 8]);
        }
    } else {
        long i = ((long)(bid - 1088) * 256 + threadIdx.x) * 8;
        f32x4 x0 = *(const f32x4*)(F + i);
        f32x4 x1 = *(const f32x4*)(F + i + 4);
        s16x8 v;
        v[0] = (short)f2bf_bits(x0[0]); v[1] = (short)f2bf_bits(x0[1]);
        v[2] = (short)f2bf_bits(x0[2]); v[3] = (short)f2bf_bits(x0[3]);
        v[4] = (short)f2bf_bits(x1[0]); v[5] = (short)f2bf_bits(x1[1]);
        v[6] = (short)f2bf_bits(x1[2]); v[7] = (short)f2bf_bits(x1[3]);
        *(s16x8*)(Fbf + i) = v;
    }
}

// ---------------------------------------------------------------------------
// K1: FW[b][rel][m][h] = sum_d F[b][m][d] * W[rel][d][h]
//   D[h][m] = wT(A) x Fbf(B), MFMA 16x16x32 bf16; distance-1 fragment dbuf.
//   rel<16  -> FW fragment-major: [(b*16+rel)*64 + m/8][h][m%8] bf16
//   rel==16 -> F2b bf16 row-major [b][n][h]
// ---------------------------------------------------------------------------
__global__ __launch_bounds__(256) void k1_fw(
        const unsigned short* __restrict__ Fbf, const unsigned short* __restrict__ wT,
        unsigned short* __restrict__ FW, unsigned short* __restrict__ F2b) {
    int bid = blockIdx.x;
    int b   = bid & 7;
    int q   = bid >> 3;          // 0..135
    int rel = q % 17;
    int mt  = q / 17;            // 0..7
    int tid = threadIdx.x;
    int w   = tid >> 6;          // 0..3
    int l   = tid & 63;
    int lg  = l >> 4;            // 0..3
    int lr  = l & 15;

    int h0 = w * 64;             // wave's 64 h-rows (M-dim)
    int m0 = mt * 64;            // block's 64 m-cols (N-dim)

    const unsigned short* wt = wT + rel * (EMB * EMB) + lg * 8;
    const unsigned short* Fb = Fbf + (long)b * (NN * EMB) + lg * 8;

    f32x4 acc[4][4];
#pragma unroll
    for (int i = 0; i < 4; ++i)
#pragma unroll
        for (int j = 0; j < 4; ++j) acc[i][j] = (f32x4){0.f, 0.f, 0.f, 0.f};

    s16x8 afr[2][4], bfr[2][4];
    // preload kk=0
#pragma unroll
    for (int hi = 0; hi < 4; ++hi)
        afr[0][hi] = *(const s16x8*)(wt + (h0 + hi * 16 + lr) * EMB);
#pragma unroll
    for (int bi = 0; bi < 4; ++bi)
        bfr[0][bi] = *(const s16x8*)(Fb + (m0 + bi * 16 + lr) * EMB);

#pragma unroll
    for (int kk = 0; kk < 8; ++kk) {
        int cur = kk & 1, nxt = cur ^ 1;
        if (kk < 7) {
            int ko = (kk + 1) * 32;
#pragma unroll
            for (int hi = 0; hi < 4; ++hi)
                afr[nxt][hi] = *(const s16x8*)(wt + (h0 + hi * 16 + lr) * EMB + ko);
#pragma unroll
            for (int bi = 0; bi < 4; ++bi)
                bfr[nxt][bi] = *(const s16x8*)(Fb + (m0 + bi * 16 + lr) * EMB + ko);
        }
#pragma unroll
        for (int hi = 0; hi < 4; ++hi)
#pragma unroll
            for (int bi = 0; bi < 4; ++bi)
                acc[hi][bi] = __builtin_amdgcn_mfma_f32_16x16x32_bf16(
                    afr[cur][hi], bfr[cur][bi], acc[hi][bi], 0, 0, 0);
    }

    // Epilogue: D rows = h, cols = m.  C layout: col = lane&15, row = (lane>>4)*4+j
#pragma unroll
    for (int hi = 0; hi < 4; ++hi) {
#pragma unroll
        for (int bi = 0; bi < 4; ++bi) {
            int m  = m0 + bi * 16 + lr;
            int kg = m >> 3, ko = m & 7;
#pragma unroll
            for (int j = 0; j < 4; ++j) {
                int h = h0 + hi * 16 + lg * 4 + j;
                if (rel < NREL)
                    FW[(long)((b * 16 + rel) * 64 + kg) * 2048 + h * 8 + ko] =
                        f2bf_bits(acc[hi][bi][j]);
                else
                    F2b[((long)b * NN + m) * EMB + h] = f2bf_bits(acc[hi][bi][j]);
            }
        }
    }
}

// ---------------------------------------------------------------------------
// K2: part[rg][b][n][h] (bf16) = sum_{r in rg(2 rels)} adj[b][r] @ FW[b][r]
//   grid 256 = 8b (XCD-pinned) x 4nt(128 rows) x 8rg(2 rels), 1 block/CU
//   block 512 thr = 8 waves = 4 wr(32-row groups) x 2 wc(K-slice parity).
//   Wave: 32 rows x 256 cols, acc[2][16].
//   Reg-staged T14 pipeline (r11-verified): per iter stage one slice-PAIR
//   (32KB, lane-contiguous conflict-free ds_write_b128), double-buffered;
//   adjacency distance-1 reg prefetch; lgkmcnt(0)+sched_barrier+raw s_barrier;
//   no vmcnt(0) in loop.  Epilogue cross-parity reduce in 2 chunks via LDS,
//   then bf16 store of partials.
// ---------------------------------------------------------------------------
__global__ __launch_bounds__(512, 2) void k2_main(
        const float* __restrict__ adj, const unsigned short* __restrict__ FW,
        unsigned short* __restrict__ part) {
    __shared__ unsigned short Blds[2][16384];   // [buf][pair: 2 slices x 8192 sh] 64KB
    int bid = blockIdx.x;
    int b   = bid & 7;
    int t   = bid >> 3;          // 0..31
    int nt  = t & 3;
    int rg  = t >> 2;            // 0..7
    int tid = threadIdx.x;
    int w   = tid >> 6;          // 0..7
    int l   = tid & 63;
    int lg  = l >> 4, lr = l & 15;
    int wr  = w >> 1;            // 0..3 : 32-row group
    int wc  = w & 1;             // 0..1 : K-slice parity

    int nrow = nt * 128 + wr * 32;    // wave's 32 output rows

    f32x4 acc0[16], acc1[16];
#pragma unroll
    for (int i = 0; i < 16; ++i) {
        acc0[i] = (f32x4){0.f, 0.f, 0.f, 0.f};
        acc1[i] = (f32x4){0.f, 0.f, 0.f, 0.f};
    }

    // adjacency: rows nrow+lr and nrow+16+lr, 32-float chunk at lg*8
    const float* adjb0 =
        adj + (((long)(b * 16 + rg * 2)) * NN + nrow + lr) * NN + lg * 8;
    const float* adjb1 = adjb0 + 16 * NN;
    const unsigned short* fwb = FW + (long)(b * 16 + rg * 2) * 131072;

    // staging: pair p (slices 2p,2p+1) = 16384 contiguous shorts at
    //   rel(p>>3)*131072 + (p&7)*16384.  Thread stages 4 x 16B lane-contiguous.
    s16x8 fwr[4];                      // one pair in flight (64B/thread)
    f32x4 ax[2][2], ay[2][2];          // [slot][row group]

#define POFF(p) ((long)((p) >> 3) * 131072 + ((p) & 7) * 16384)

    // ---- prologue ----
    {   // pair 0: load regs, write buf0
        const unsigned short* s = fwb + POFF(0) + tid * 8;
#pragma unroll
        for (int c = 0; c < 4; ++c) fwr[c] = *(const s16x8*)(s + c * 4096);
#pragma unroll
        for (int c = 0; c < 4; ++c)
            *(s16x8*)(&Blds[0][c * 4096 + tid * 8]) = fwr[c];
    }
    {   // adjacency slice wc -> slot 0 (both row groups)
        const float* p0 = adjb0 + wc * 32;
        const float* p1 = adjb1 + wc * 32;
        ax[0][0] = *(const f32x4*)p0; ay[0][0] = *(const f32x4*)(p0 + 4);
        ax[0][1] = *(const f32x4*)p1; ay[0][1] = *(const f32x4*)(p1 + 4);
    }
    {   // pair 1 regs
        const unsigned short* s = fwb + POFF(1) + tid * 8;
#pragma unroll
        for (int c = 0; c < 4; ++c) fwr[c] = *(const s16x8*)(s + c * 4096);
    }
    asm volatile("s_waitcnt lgkmcnt(0)" ::: "memory");
    __builtin_amdgcn_sched_barrier(0);
    __builtin_amdgcn_s_barrier();
    asm volatile("" ::: "memory");

#pragma unroll
    for (int i = 0; i < 16; ++i) {
        // 1. issue adjacency slice 2(i+1)+wc into the other slot
        if (i + 1 < 16) {
            int sl = 2 * (i + 1) + wc;
            long ao = (long)(sl >> 4) * (NN * NN) + (sl & 15) * 32;
            const float* p0 = adjb0 + ao;
            const float* p1 = adjb1 + ao;
            if (((i + 1) & 1) == 0) {
                ax[0][0] = *(const f32x4*)p0; ay[0][0] = *(const f32x4*)(p0 + 4);
                ax[0][1] = *(const f32x4*)p1; ay[0][1] = *(const f32x4*)(p1 + 4);
            } else {
                ax[1][0] = *(const f32x4*)p0; ay[1][0] = *(const f32x4*)(p0 + 4);
                ax[1][1] = *(const f32x4*)p1; ay[1][1] = *(const f32x4*)(p1 + 4);
            }
        }

        // 2. compute slice 2i+wc from Blds[i&1] (parity half wc)
        f32x4 x00 = ax[i & 1][0], x01 = ay[i & 1][0];
        f32x4 x10 = ax[i & 1][1], x11 = ay[i & 1][1];
        s16x8 a0, a1;
        a0[0] = (short)f2bf_hw(x00[0]); a0[1] = (short)f2bf_hw(x00[1]);
        a0[2] = (short)f2bf_hw(x00[2]); a0[3] = (short)f2bf_hw(x00[3]);
        a0[4] = (short)f2bf_hw(x01[0]); a0[5] = (short)f2bf_hw(x01[1]);
        a0[6] = (short)f2bf_hw(x01[2]); a0[7] = (short)f2bf_hw(x01[3]);
        a1[0] = (short)f2bf_hw(x10[0]); a1[1] = (short)f2bf_hw(x10[1]);
        a1[2] = (short)f2bf_hw(x10[2]); a1[3] = (short)f2bf_hw(x10[3]);
        a1[4] = (short)f2bf_hw(x11[0]); a1[5] = (short)f2bf_hw(x11[1]);
        a1[6] = (short)f2bf_hw(x11[2]); a1[7] = (short)f2bf_hw(x11[3]);

        const unsigned short* bl = &Blds[i & 1][wc * 8192 + lg * 2048];
#pragma unroll
        for (int f = 0; f < 16; ++f) {
            s16x8 bf = *(const s16x8*)(bl + (f * 16 + lr) * 8);
            acc0[f] = __builtin_amdgcn_mfma_f32_16x16x32_bf16(a0, bf, acc0[f], 0, 0, 0);
            acc1[f] = __builtin_amdgcn_mfma_f32_16x16x32_bf16(a1, bf, acc1[f], 0, 0, 0);
        }
        asm volatile("" ::: "memory");   // ds_reads above, ds_writes below

        // 3. ds_write pair i+1; 4. issue pair i+2 regs; barrier
        if (i + 1 < 16) {
            unsigned short* dst = &Blds[(i + 1) & 1][tid * 8];
#pragma unroll
            for (int c = 0; c < 4; ++c) *(s16x8*)(dst + c * 4096) = fwr[c];
            if (i + 2 < 16) {
                const unsigned short* s = fwb + POFF(i + 2) + tid * 8;
#pragma unroll
                for (int c = 0; c < 4; ++c) fwr[c] = *(const s16x8*)(s + c * 4096);
            }
            asm volatile("s_waitcnt lgkmcnt(0)" ::: "memory");
            __builtin_amdgcn_sched_barrier(0);
            __builtin_amdgcn_s_barrier();
            asm volatile("" ::: "memory");
        }
    }
#undef POFF

    // ---- cross-wc reduce via LDS, 2 chunks (g = row-group), bf16 store
    float* lf = (float*)Blds;          // 16384 floats = 64KB
    unsigned short* pp = part + ((long)rg * BS + b) * (NN * EMB);
#pragma unroll
    for (int g = 0; g < 2; ++g) {
        __syncthreads();
        if (wc == 1) {
#pragma unroll
            for (int f = 0; f < 16; ++f)
#pragma unroll
                for (int j = 0; j < 4; ++j)
                    lf[wr * 4096 + (f * 4 + j) * 64 + l] =
                        g ? acc1[f][j] : acc0[f][j];
        }
        __syncthreads();
        if (wc == 0) {
#pragma unroll
            for (int f = 0; f < 16; ++f) {
                int h = f * 16 + lr;
#pragma unroll
                for (int j = 0; j < 4; ++j) {
                    int n = nrow + g * 16 + lg * 4 + j;
                    float v = (g ? acc1[f][j] : acc0[f][j]) +
                              lf[wr * 4096 + (f * 4 + j) * 64 + l];
                    pp[(long)n * EMB + h] = f2bf_bits(v);
                }
            }
        }
    }
}

// ---------------------------------------------------------------------------
// K3: out = relu(sum over 8 bf16 part slices + F2b), 8 elems/thread
// ---------------------------------------------------------------------------
__global__ __launch_bounds__(256) void k3_reduce(
        const unsigned short* __restrict__ part,
        const unsigned short* __restrict__ F2b, float* __restrict__ out) {
    const long PS = (long)BS * NN * EMB;   // elements per rg slice
    long i = ((long)blockIdx.x * 256 + threadIdx.x) * 8;
    float s[8];
    {
        s16x8 v = *(const s16x8*)(F2b + i);
#pragma unroll
        for (int j = 0; j < 8; ++j) s[j] = bf2f((unsigned short)v[j]);
    }
#pragma unroll
    for (int rg = 0; rg < 8; ++rg) {
        s16x8 v = *(const s16x8*)(part + (long)rg * PS + i);
#pragma unroll
        for (int j = 0; j < 8; ++j) s[j] += bf2f((unsigned short)v[j]);
    }
    f32x4 r0, r1;
#pragma unroll
    for (int j = 0; j < 4; ++j) {
        r0[j] = s[j] > 0.f ? s[j] : 0.f;
        r1[j] = s[j + 4] > 0.f ? s[j + 4] : 0.f;
    }
    *(f32x4*)(out + i) = r0;
    *(f32x4*)(out + i + 4) = r1;
}

// ---------------------------------------------------------------------------
extern "C" void kernel_launch(void* const* d_in, const int* in_sizes, int n_in,
                              void* d_out, int out_size, void* d_ws, size_t ws_size,
                              hipStream_t stream) {
    const float* F   = (const float*)d_in[0];   // [8][512][256]
    const float* adj = (const float*)d_in[1];   // [8][16][512][512]
    const float* Wr  = (const float*)d_in[2];   // [16][256][256]
    const float* W0  = (const float*)d_in[3];   // [256][256]
    float* out = (float*)d_out;                 // [8][512][256]

    unsigned short* wT   = (unsigned short*)d_ws;            // 17*256*256 bf16
    unsigned short* Fbf  = wT + 17 * 256 * 256;              // 8*512*256 bf16
    unsigned short* FW   = Fbf + (long)8 * 512 * 256;        // 8*16*64*2048 bf16
    unsigned short* F2b  = FW + (long)8 * 16 * 64 * 2048;    // 8*512*256 bf16
    unsigned short* part = F2b + (long)8 * 512 * 256;        // 8 slices bf16

    k0_prep<<<1600, 256, 0, stream>>>(Wr, W0, F, wT, Fbf);
    k1_fw<<<1088, 256, 0, stream>>>(Fbf, wT, FW, F2b);
    k2_main<<<256, 512, 0, stream>>>(adj, FW, part);
    k3_reduce<<<512, 256, 0, stream>>>(part, F2b, out);
}